// Round 6
// baseline (614.722 us; speedup 1.0000x reference)
//
#include <hip/hip_runtime.h>

// GraphConv: B=16, S=50000, FIN=FOUT=16, T=64, E=8M
// R6: R5 post-mortem — fine-grained flush amplification is per-REC (~72B
// extra write) and scales with bin count, not run length (R3 965MB / R4
// 715MB / R5 626MB); 49-bin part1 is clean. So: eliminate the fine
// partition pass entirely. part1 scatters into fixed coarse slabs
// (cursor1[b]=b*CAPC, no hist/scan needed); k_pull (one block per
// 1024-row fine bin) STREAMS its parent coarse slab from L3, filters
// matches via ballot-compaction (1 leader LDS-atomic per wave-iter),
// then runs the proven ballot index-sort + per-row register gather.
#define BNUM 16
#define NCOL 800000   // S*FIN
#define NROW 800000   // S*FOUT
#define CSH  14       // coarse shift (16384 rows)
#define NC   49       // coarse bins
#define CB   64       // padded coarse bin count (6-bit key)
#define CAPC 166912   // slab capacity per coarse bin (mean 163265, +9 sigma)
#define PR   8192     // edges per part1 block
#define CAP  11264    // pull LDS capacity (fine-bin mean 10240, +10 sigma)
#define OVF  64       // overflow queue
#define NBIN 784      // fine bins = 49*16 (1024 rows each)

#define WG_ADD(p, v) __hip_atomic_fetch_add((p), (v), __ATOMIC_RELAXED, __HIP_MEMORY_SCOPE_WORKGROUP)

// ---- bf16 <-> f32 helpers (bit-exact RNE) ----
__device__ __forceinline__ unsigned short f2bf(float f) {
    unsigned u = __float_as_uint(f);
    unsigned r = (u + 0x7fffu + ((u >> 16) & 1u)) >> 16;   // round-nearest-even
    return (unsigned short)r;
}
__device__ __forceinline__ float bf2f(unsigned short h) {
    return __uint_as_float(((unsigned)h) << 16);
}

// ballot-based equal-key mask + rank within group (wave-parallel, no atomics)
template <int BITS>
__device__ __forceinline__ void brank(unsigned key, bool v, int lane,
                                      int& rank, int& gsz) {
    unsigned long long vm = __ballot(v);
    unsigned long long eq = ~0ull;
#pragma unroll
    for (int b = 0; b < BITS; ++b) {
        unsigned long long bb = __ballot((key >> b) & 1u);
        eq &= ((key >> b) & 1u) ? bb : ~bb;
    }
    eq &= vm;
    rank = __popcll(eq & ((1ull << lane) - 1ull));
    gsz  = __popcll(eq);
}

// x [16][800000] f32 (b-major) -> xT [800000][16] bf16 (c-major, 32B per c)
__global__ __launch_bounds__(256) void k_transpose_x(const float* __restrict__ x,
                                                     unsigned* __restrict__ xT) {
    int c = blockIdx.x * 256 + threadIdx.x;
    if (c >= NCOL) return;
    unsigned p[8];
#pragma unroll
    for (int b = 0; b < 8; ++b) {
        float lo = x[(size_t)(2 * b)     * NCOL + c];
        float hi = x[(size_t)(2 * b + 1) * NCOL + c];
        p[b] = (unsigned)f2bf(lo) | ((unsigned)f2bf(hi) << 16);
    }
    uint4* dst = reinterpret_cast<uint4*>(xT + (size_t)c * 8);
    dst[0] = make_uint4(p[0], p[1], p[2], p[3]);
    dst[1] = make_uint4(p[4], p[5], p[6], p[7]);
}

// init slab cursors: cursor1[b] = b * CAPC
__global__ __launch_bounds__(64) void k_init(unsigned* __restrict__ cursor1) {
    int t = threadIdx.x;
    if (t < CB) cursor1[t] = (unsigned)t * CAPC;
}

// Coarse multisplit by row>>14 into fixed slabs (proven-clean: 49 dests).
// recA1 = col | type<<20 | (row>>16)<<26 ; recB1 = row & 0xFFFF.
__global__ __launch_bounds__(1024) void k_part1(const int* __restrict__ rows,
                                                const int* __restrict__ cols,
                                                const int* __restrict__ et,
                                                unsigned* __restrict__ cursor1,
                                                unsigned* __restrict__ recA1,
                                                unsigned short* __restrict__ recB1,
                                                int E) {
    __shared__ unsigned short h16[16][CB];      // 2KB wave-private hist/cursor
    __shared__ unsigned srtP[PR];               // 32KB payload
    __shared__ unsigned srtK[PR];               // 32KB raw row
    __shared__ unsigned gadj[CB];

    int tid = threadIdx.x, lane = tid & 63, wv = tid >> 6;
    int c0 = blockIdx.x * PR;
    unsigned* hw = (unsigned*)h16;
    for (int i = tid; i < 16 * CB / 2; i += 1024) hw[i] = 0u;
    __syncthreads();

    unsigned er[8], ec[8];
#pragma unroll
    for (int c = 0; c < 8; ++c) {
        int idx = c0 + c * 1024 + tid;
        if (idx < E) {
            unsigned r  = (unsigned)__builtin_nontemporal_load(rows + idx);
            unsigned cc = (unsigned)__builtin_nontemporal_load(cols + idx);
            unsigned ty = (unsigned)__builtin_nontemporal_load(et + idx);
            er[c] = r;
            ec[c] = cc | (ty << 20) | ((r >> 16) << 26);
        } else {
            er[c] = 0xFFFFFFFFu; ec[c] = 0u;
        }
    }

    // phase A: ballot-ranked wave-private histogram
#pragma unroll
    for (int c = 0; c < 8; ++c) {
        bool v = er[c] != 0xFFFFFFFFu;
        unsigned key = (er[c] >> CSH) & (CB - 1);
        int rank, gsz;
        brank<6>(key, v, lane, rank, gsz);
        if (v && rank == 0)
            h16[wv][key] = (unsigned short)(h16[wv][key] + (unsigned)gsz);
    }
    __syncthreads();

    // scan 64 bins in wave 0 + slab reservation
    if (tid < CB) {
        unsigned t0 = 0;
#pragma unroll
        for (int ww = 0; ww < 16; ++ww) {
            unsigned a = h16[ww][tid]; h16[ww][tid] = (unsigned short)t0; t0 += a;
        }
        unsigned incl = t0;
        for (int off = 1; off < 64; off <<= 1) {
            unsigned n = __shfl_up(incl, off, 64);
            if (tid >= off) incl += n;
        }
        unsigned ex = incl - t0;
        gadj[tid] = (t0 ? atomicAdd(&cursor1[tid], t0) : 0u) - ex;
#pragma unroll
        for (int ww = 0; ww < 16; ++ww)
            h16[ww][tid] = (unsigned short)(h16[ww][tid] + ex);
    }
    __syncthreads();

    // phase B: place into LDS sorted order
#pragma unroll
    for (int c = 0; c < 8; ++c) {
        bool v = er[c] != 0xFFFFFFFFu;
        unsigned key = (er[c] >> CSH) & (CB - 1);
        int rank, gsz;
        brank<6>(key, v, lane, rank, gsz);
        unsigned cur = h16[wv][key];
        if (v && rank == 0)
            h16[wv][key] = (unsigned short)(cur + (unsigned)gsz);
        if (v) {
            unsigned d = cur + (unsigned)rank;
            srtP[d] = ec[c];
            srtK[d] = er[c];
        }
    }
    __syncthreads();

    // flush long runs (~167 recs) into slabs; guard slab overflow
    int tot = min(PR, E - c0);
    for (int j = tid; j < tot; j += 1024) {
        unsigned rr = srtK[j], key = rr >> CSH;
        unsigned dst = gadj[key] + (unsigned)j;
        if (dst < (key + 1u) * CAPC) {
            recA1[dst] = srtP[j];
            recB1[dst] = (unsigned short)(rr & 0xFFFFu);
        }
    }
}

__device__ __forceinline__ void fma8(float* a, float wt, uint4 v, int base) {
    a[base + 0] += wt * bf2f((unsigned short)(v.x & 0xffffu));
    a[base + 1] += wt * bf2f((unsigned short)(v.x >> 16));
    a[base + 2] += wt * bf2f((unsigned short)(v.y & 0xffffu));
    a[base + 3] += wt * bf2f((unsigned short)(v.y >> 16));
    a[base + 4] += wt * bf2f((unsigned short)(v.z & 0xffffu));
    a[base + 5] += wt * bf2f((unsigned short)(v.z >> 16));
    a[base + 6] += wt * bf2f((unsigned short)(v.w & 0xffffu));
    a[base + 7] += wt * bf2f((unsigned short)(v.w >> 16));
}

// One block per 1024-row fine bin: stream parent coarse slab (L3-resident),
// ballot-compact matching recs into LDS, proven ballot index-sort by lrow,
// per-row register gather, coalesced store. Zero fine-grained global writes.
__global__ __launch_bounds__(1024) void k_pull(const unsigned* __restrict__ recA1,
                                               const unsigned short* __restrict__ recB1,
                                               const unsigned* __restrict__ cursor1,
                                               const float* __restrict__ wt_tab,
                                               const unsigned* __restrict__ xT,
                                               float* __restrict__ out) {
    __shared__ unsigned short h16[16][1024];   // 32KB wave-private hist/cursor
    __shared__ unsigned srtP[CAP];             // 45KB payload (col|type), unsorted
    __shared__ unsigned short lrowA[CAP];      // 22.5KB local row per rec
    __shared__ unsigned short srtI[CAP];       // 22.5KB sorted index
    __shared__ unsigned short ptr_[1025];      // 2KB row offsets
    __shared__ unsigned wsum[16];
    __shared__ unsigned nsel, novf;
    __shared__ unsigned ovfP[OVF];
    __shared__ unsigned short ovfR[OVF];

    int tid = threadIdx.x, lane = tid & 63, wv = tid >> 6;
    int bin = blockIdx.x;                      // 0..783
    int cb  = bin >> 4;
    unsigned cbeg = (unsigned)cb * CAPC;
    unsigned cend = min(cursor1[cb], cbeg + (unsigned)CAPC);

    unsigned* hw = (unsigned*)h16;
    for (int i = tid; i < 16 * 1024 / 2; i += 1024) hw[i] = 0u;
    if (tid == 0) { nsel = 0u; novf = 0u; }
    __syncthreads();

    // stream + filter + ballot compaction (1 leader LDS-atomic per wave-iter)
    for (unsigned i0 = cbeg; i0 < cend; i0 += 1024) {
        unsigned i = i0 + (unsigned)tid;
        bool v = i < cend;
        unsigned a = 0u, b = 0u;
        if (v) { a = recA1[i]; b = recB1[i]; }
        unsigned row = ((a >> 26) << 16) | b;
        bool m = v && (row >> 10) == (unsigned)bin;
        unsigned long long mk = __ballot(m);
        int rank = __popcll(mk & ((1ull << lane) - 1ull));
        int cnt  = __popcll(mk);
        unsigned sb = 0u;
        if (lane == 0 && cnt) sb = WG_ADD(&nsel, (unsigned)cnt);
        sb = __shfl(sb, 0);
        if (m) {
            unsigned slot = sb + (unsigned)rank;
            if (slot < CAP) {
                srtP[slot]  = a & 0x03FFFFFFu;
                lrowA[slot] = (unsigned short)(row & 1023u);
            } else {
                unsigned o = WG_ADD(&novf, 1u);
                if (o < OVF) { ovfP[o] = a & 0x03FFFFFFu;
                               ovfR[o] = (unsigned short)(row & 1023u); }
            }
        }
    }
    __syncthreads();
    int n  = min((int)nsel, CAP);
    int nr = (n + 1023) >> 10;

    // phase A: ballot histogram by lrow (LDS-resident input)
    for (int c = 0; c < nr; ++c) {
        int idx = c * 1024 + tid;
        bool v = idx < n;
        unsigned key = v ? (unsigned)lrowA[idx] : 0u;
        int rank, gsz;
        brank<10>(key, v, lane, rank, gsz);
        if (v && rank == 0)
            h16[wv][key] = (unsigned short)(h16[wv][key] + (unsigned)gsz);
    }
    __syncthreads();

    // scan 1024 row-bins (1/thread): wave prefix into h16, block scan -> ptr_
    {
        unsigned t0 = 0;
#pragma unroll
        for (int ww = 0; ww < 16; ++ww) {
            unsigned a = h16[ww][tid]; h16[ww][tid] = (unsigned short)t0; t0 += a;
        }
        unsigned incl = t0;
        for (int off = 1; off < 64; off <<= 1) {
            unsigned m = __shfl_up(incl, off, 64);
            if ((tid & 63) >= off) incl += m;
        }
        if ((tid & 63) == 63) wsum[tid >> 6] = incl;
        __syncthreads();
        unsigned pre = 0;
        for (int k = 0; k < (tid >> 6); ++k) pre += wsum[k];
        unsigned ex = pre + incl - t0;
        ptr_[tid] = (unsigned short)ex;
        if (tid == 1023) ptr_[1024] = (unsigned short)n;
#pragma unroll
        for (int ww = 0; ww < 16; ++ww)
            h16[ww][tid] = (unsigned short)(h16[ww][tid] + ex);
    }
    __syncthreads();

    // phase B: ballot-place sorted INDEX
    for (int c = 0; c < nr; ++c) {
        int idx = c * 1024 + tid;
        bool v = idx < n;
        unsigned key = v ? (unsigned)lrowA[idx] : 0u;
        int rank, gsz;
        brank<10>(key, v, lane, rank, gsz);
        unsigned cur = h16[wv][key];
        if (v && rank == 0)
            h16[wv][key] = (unsigned short)(cur + (unsigned)gsz);
        if (v) srtI[cur + (unsigned)rank] = (unsigned short)idx;
    }
    __syncthreads();

    // gather: 1 thread per row, register accumulate, 2-deep pipeline
    int r = tid;
    float a[16];
#pragma unroll
    for (int k = 0; k < 16; ++k) a[k] = 0.f;
    {
        int p0 = (int)ptr_[r];
        int p1 = (int)ptr_[r + 1];
        uint4 lo = make_uint4(0, 0, 0, 0), hi = lo;
        unsigned u = 0u;
        int p = p0;
        if (p < p1) {
            u = srtP[srtI[p]];
            const uint4* q = reinterpret_cast<const uint4*>(xT + (size_t)(u & 0xFFFFFu) * 8);
            lo = q[0]; hi = q[1];
        }
        while (p < p1) {
            int pn = p + 1;
            unsigned un = 0u;
            uint4 lon = make_uint4(0, 0, 0, 0), hin = lon;
            if (pn < p1) {
                un = srtP[srtI[pn]];
                const uint4* qn = reinterpret_cast<const uint4*>(xT + (size_t)(un & 0xFFFFFu) * 8);
                lon = qn[0]; hin = qn[1];
            }
            float wt = wt_tab[u >> 20];
            fma8(a, wt, lo, 0);
            fma8(a, wt, hi, 8);
            u = un; lo = lon; hi = hin; p = pn;
        }
    }

    // overflow add-in (statistically never populated)
    {
        unsigned no = min(novf, (unsigned)OVF);
        for (unsigned o = 0; o < no; ++o) {
            if ((int)ovfR[o] == r) {
                unsigned u = ovfP[o];
                const uint4* q = reinterpret_cast<const uint4*>(xT + (size_t)(u & 0xFFFFFu) * 8);
                uint4 vlo = q[0], vhi = q[1];
                float wt = wt_tab[u >> 20];
                fma8(a, wt, vlo, 0);
                fma8(a, wt, vhi, 8);
            }
        }
    }

    int gr = bin * 1024 + r;
    if (gr < NROW) {
#pragma unroll
        for (int k = 0; k < 16; ++k)
            __builtin_nontemporal_store(a[k], out + (size_t)k * NROW + gr);
    }
}

// ---------------- fallback path (atomic scatter, needs only 51.2MB) ----

__global__ __launch_bounds__(256) void k_scatter(const int* __restrict__ rows,
                                                 const int* __restrict__ cols,
                                                 const int* __restrict__ et,
                                                 const float* __restrict__ w,
                                                 const unsigned* __restrict__ xT,
                                                 unsigned short* __restrict__ outT,
                                                 int E) {
    long long tid = (long long)blockIdx.x * 256 + threadIdx.x;
    long long e = tid >> 3;
    if (e >= E) return;
    int j = (int)(tid & 7);
    int r = __builtin_nontemporal_load(rows + e);
    int c = __builtin_nontemporal_load(cols + e);
    int t = __builtin_nontemporal_load(et + e);
    float wt = w[t];
    unsigned px = xT[(size_t)c * 8 + j];
    float x0 = bf2f((unsigned short)(px & 0xffffu));
    float x1 = bf2f((unsigned short)(px >> 16));
    unsigned short b0 = f2bf(wt * x0);
    unsigned short b1 = f2bf(wt * x1);
    unsigned data = (unsigned)b0 | ((unsigned)b1 << 16);
    unsigned short* dst = outT + ((size_t)r * 16 + 2 * j);
    asm volatile("global_atomic_pk_add_bf16 %0, %1, off"
                 :: "v"(dst), "v"(data) : "memory");
}

__global__ __launch_bounds__(256) void k_transpose_out(const unsigned* __restrict__ outT,
                                                       float* __restrict__ out) {
    int r = blockIdx.x * 256 + threadIdx.x;
    if (r >= NROW) return;
    const uint4* src = reinterpret_cast<const uint4*>(outT + (size_t)r * 8);
    uint4 v0 = src[0], v1 = src[1];
    unsigned p[8] = {v0.x, v0.y, v0.z, v0.w, v1.x, v1.y, v1.z, v1.w};
#pragma unroll
    for (int b = 0; b < 8; ++b) {
        out[(size_t)(2 * b)     * NROW + r] = bf2f((unsigned short)(p[b] & 0xffffu));
        out[(size_t)(2 * b + 1) * NROW + r] = bf2f((unsigned short)(p[b] >> 16));
    }
}

extern "C" void kernel_launch(void* const* d_in, const int* in_sizes, int n_in,
                              void* d_out, int out_size, void* d_ws, size_t ws_size,
                              hipStream_t stream) {
    const float* x    = (const float*)d_in[0];
    const float* w    = (const float*)d_in[1];
    const int*   rows = (const int*)d_in[2];
    const int*   cols = (const int*)d_in[3];
    const int*   et   = (const int*)d_in[4];
    const int    E    = in_sizes[2];

    float* out = (float*)d_out;

    // ws layout: xT 25.6MB | recA1 u32[NC*CAPC] | recB1 u16[NC*CAPC] | cursor1[64]
    size_t xT_b    = (size_t)NCOL * 8 * 4;            // 25,600,000
    size_t slabN   = (size_t)NC * CAPC;               // 8,178,688 recs
    size_t b1A_off = xT_b;
    size_t b1B_off = b1A_off + slabN * 4;
    size_t aux_off = (b1B_off + slabN * 2 + 255) & ~(size_t)255;
    size_t needed  = aux_off + (size_t)CB * 4;

    unsigned* xT = (unsigned*)d_ws;

    if (ws_size >= needed) {
        unsigned*       recA1   = (unsigned*)((char*)d_ws + b1A_off);
        unsigned short* recB1   = (unsigned short*)((char*)d_ws + b1B_off);
        unsigned*       cursor1 = (unsigned*)((char*)d_ws + aux_off);

        k_init<<<1, 64, 0, stream>>>(cursor1);
        k_transpose_x<<<NCOL / 256, 256, 0, stream>>>(x, xT);

        int pblocks = (E + PR - 1) / PR;
        k_part1<<<pblocks, 1024, 0, stream>>>(rows, cols, et, cursor1, recA1, recB1, E);
        k_pull<<<NBIN, 1024, 0, stream>>>(recA1, recB1, cursor1, w, xT, out);
    } else {
        // fallback: pk_add_bf16 atomic scatter (51.2MB ws)
        unsigned short* outT = (unsigned short*)d_ws;
        unsigned*       xT2  = (unsigned*)((char*)d_ws + (size_t)NROW * BNUM * 2);

        hipMemsetAsync(outT, 0, (size_t)NROW * BNUM * 2, stream);
        k_transpose_x<<<NCOL / 256, 256, 0, stream>>>(x, xT2);

        long long total = (long long)E * 8;
        int blocks = (int)((total + 255) / 256);
        k_scatter<<<blocks, 256, 0, stream>>>(rows, cols, et, w, xT2, outT, E);
        k_transpose_out<<<NROW / 256, 256, 0, stream>>>((const unsigned*)outT, out);
    }
}

// Round 7
// 268.441 us; speedup vs baseline: 2.2900x; 2.2900x over previous
//
#include <hip/hip_runtime.h>

// GraphConv: B=16, S=50000, FIN=FOUT=16, T=64, E=8M
// R7: synthesis of measured-best components. R6's streaming filter (530us,
// 16x read-amp at 1 block/CU) falsified; fine-flush write-amp (~13x/rec)
// is invariant to run length/threads (R3/R4/R5) - accept it, minimize
// everything else. Pipeline: transpose (13us) | k_place = R2's proven
// 512-thread LDS-atomic-ranked multisplit (fastest fine partition
// measured, ~110-165us) writing into FIXED PER-BIN SLABS (deletes
// k_hist+k_scan, ~55us) | k_pull = R4's proven ballot-sort pull
// (VGPR~32, 2 blocks/CU, ~140-175us).
#define BNUM 16
#define NCOL 800000   // S*FIN
#define NROW 800000   // S*FOUT
#define RPB  1024     // rows per fine bin
#define NBIN 782      // ceil(NROW/RPB)
#define HB   1024     // padded bin count (10-bit key)
#define PR   8192     // edges per place block
#define PT   512      // place threads (16 edges/thread)
#define CAPF 11264    // slab capacity per bin (mean 10240, +10 sigma)

#define WG_ADD(p, v) __hip_atomic_fetch_add((p), (v), __ATOMIC_RELAXED, __HIP_MEMORY_SCOPE_WORKGROUP)

// ---- bf16 <-> f32 helpers (bit-exact RNE) ----
__device__ __forceinline__ unsigned short f2bf(float f) {
    unsigned u = __float_as_uint(f);
    unsigned r = (u + 0x7fffu + ((u >> 16) & 1u)) >> 16;   // round-nearest-even
    return (unsigned short)r;
}
__device__ __forceinline__ float bf2f(unsigned short h) {
    return __uint_as_float(((unsigned)h) << 16);
}

// ballot-based equal-key mask + rank within group (wave-parallel, no atomics)
template <int BITS>
__device__ __forceinline__ void brank(unsigned key, bool v, int lane,
                                      int& rank, int& gsz) {
    unsigned long long vm = __ballot(v);
    unsigned long long eq = ~0ull;
#pragma unroll
    for (int b = 0; b < BITS; ++b) {
        unsigned long long bb = __ballot((key >> b) & 1u);
        eq &= ((key >> b) & 1u) ? bb : ~bb;
    }
    eq &= vm;
    rank = __popcll(eq & ((1ull << lane) - 1ull));
    gsz  = __popcll(eq);
}

// x [16][800000] f32 (b-major) -> xT [800000][16] bf16 (c-major, 32B per c)
__global__ __launch_bounds__(256) void k_transpose_x(const float* __restrict__ x,
                                                     unsigned* __restrict__ xT) {
    int c = blockIdx.x * 256 + threadIdx.x;
    if (c >= NCOL) return;
    unsigned p[8];
#pragma unroll
    for (int b = 0; b < 8; ++b) {
        float lo = x[(size_t)(2 * b)     * NCOL + c];
        float hi = x[(size_t)(2 * b + 1) * NCOL + c];
        p[b] = (unsigned)f2bf(lo) | ((unsigned)f2bf(hi) << 16);
    }
    uint4* dst = reinterpret_cast<uint4*>(xT + (size_t)c * 8);
    dst[0] = make_uint4(p[0], p[1], p[2], p[3]);
    dst[1] = make_uint4(p[4], p[5], p[6], p[7]);
}

// init slab cursors: cursor[b] = b * CAPF
__global__ __launch_bounds__(1024) void k_init(unsigned* __restrict__ cursor) {
    int t = threadIdx.x;
    cursor[t] = (unsigned)t * CAPF;
}

// R2-verbatim coalescing multisplit (512 threads, 16 edges/thread in regs,
// LDS-atomic two-phase ranking, 76KB LDS -> 2 blocks/CU), slab-based
// global reservation (no hist/scan). recA = col|type<<20, recB = lrow.
__global__ __launch_bounds__(PT) void k_place(const int* __restrict__ rows,
                                              const int* __restrict__ cols,
                                              const int* __restrict__ et,
                                              unsigned* __restrict__ cursor,
                                              unsigned* __restrict__ recA,
                                              unsigned short* __restrict__ recB,
                                              int E) {
    __shared__ unsigned cnt[HB];      // hist, then reused as rank cursor
    __shared__ unsigned lofs[HB];     // local exclusive offsets
    __shared__ unsigned gbase[HB];    // reserved slab bases
    __shared__ unsigned srtA[PR];     // col|type, bin-sorted
    __shared__ unsigned srtR[PR];     // (bin<<10) | lrow
    __shared__ unsigned wsum[8];

    int t  = threadIdx.x;
    int c0 = blockIdx.x * PR;
    int c1 = min(E, c0 + PR);
    int tot = c1 - c0;

    for (int i = t; i < HB; i += PT) cnt[i] = 0u;
    __syncthreads();

    // load 16 edges/thread into registers (statically indexed)
    unsigned er[16], ec[16];
#pragma unroll
    for (int k = 0; k < 16; ++k) {
        int e = c0 + k * PT + t;
        if (e < c1) {
            int r  = __builtin_nontemporal_load(rows + e);
            int c  = __builtin_nontemporal_load(cols + e);
            int ty = __builtin_nontemporal_load(et + e);
            er[k] = (unsigned)r;
            ec[k] = (unsigned)c | ((unsigned)ty << 20);
        } else {
            er[k] = 0xFFFFFFFFu;
            ec[k] = 0u;
        }
    }
    // local hist
#pragma unroll
    for (int k = 0; k < 16; ++k)
        if (er[k] != 0xFFFFFFFFu) WG_ADD(&cnt[er[k] >> 10], 1u);
    __syncthreads();

    // exclusive scan of cnt[1024] (2 entries/thread, wave shuffle scan)
    {
        unsigned a0 = cnt[2 * t];
        unsigned a1 = cnt[2 * t + 1];
        unsigned ts = a0 + a1;
        unsigned incl = ts;
        for (int off = 1; off < 64; off <<= 1) {
            unsigned n = __shfl_up(incl, off, 64);
            if ((t & 63) >= off) incl += n;
        }
        if ((t & 63) == 63) wsum[t >> 6] = incl;
        __syncthreads();
        unsigned pre = 0;
        for (int k2 = 0; k2 < (t >> 6); ++k2) pre += wsum[k2];
        unsigned ex = pre + incl - ts;
        lofs[2 * t]     = ex;
        lofs[2 * t + 1] = ex + a0;
    }
    __syncthreads();

    // reserve slab ranges (one global atomic per non-empty bin)
    for (int i = t; i < HB; i += PT) {
        unsigned c = cnt[i];
        gbase[i] = c ? atomicAdd(&cursor[i], c) : 0u;
    }
    __syncthreads();
    for (int i = t; i < HB; i += PT) cnt[i] = 0u;   // reuse as rank cursor
    __syncthreads();

    // ranked place into LDS (bin-sorted order)
#pragma unroll
    for (int k = 0; k < 16; ++k) {
        if (er[k] == 0xFFFFFFFFu) continue;
        unsigned b  = er[k] >> 10;
        unsigned lr = er[k] & 1023u;
        unsigned rk = WG_ADD(&cnt[b], 1u);
        unsigned j  = lofs[b] + rk;
        srtA[j] = ec[k];
        srtR[j] = (b << 10) | lr;
    }
    __syncthreads();

    // flush: consecutive j within a bin run -> consecutive slab dst
    for (int j = t; j < tot; j += PT) {
        unsigned rr = srtR[j];
        unsigned b  = rr >> 10;
        unsigned dst = gbase[b] + ((unsigned)j - lofs[b]);
        if (dst < (b + 1u) * CAPF) {            // slab overflow guard (~1e-25)
            recA[dst] = srtA[j];
            recB[dst] = (unsigned short)(rr & 1023u);
        }
    }
}

__device__ __forceinline__ void fma8(float* a, float wt, uint4 v, int base) {
    a[base + 0] += wt * bf2f((unsigned short)(v.x & 0xffffu));
    a[base + 1] += wt * bf2f((unsigned short)(v.x >> 16));
    a[base + 2] += wt * bf2f((unsigned short)(v.y & 0xffffu));
    a[base + 3] += wt * bf2f((unsigned short)(v.y >> 16));
    a[base + 4] += wt * bf2f((unsigned short)(v.z & 0xffffu));
    a[base + 5] += wt * bf2f((unsigned short)(v.z >> 16));
    a[base + 6] += wt * bf2f((unsigned short)(v.w & 0xffffu));
    a[base + 7] += wt * bf2f((unsigned short)(v.w >> 16));
}

// R4-verbatim pull on slab bins: ballot counting-sort by lrow (atomic-free),
// 1 thread/row register accumulate, coalesced store. Recs (re)loaded with
// cached loads (L2-hot on second pass). 79KB LDS, VGPR~32 -> 2 blocks/CU.
__global__ __launch_bounds__(1024) void k_pull(const unsigned* __restrict__ cursor,
                                               const unsigned* __restrict__ recA,
                                               const unsigned short* __restrict__ recB,
                                               const float* __restrict__ wt_tab,
                                               const unsigned* __restrict__ xT,
                                               float* __restrict__ out) {
    __shared__ unsigned short h16[16][RPB];    // 32KB wave-private hist/cursor
    __shared__ unsigned srt[CAPF];             // 44KB sorted payload
    __shared__ unsigned short ptr_[RPB + 1];   // 2KB row offsets
    __shared__ unsigned wsum[16];

    int tid = threadIdx.x, lane = tid & 63, wv = tid >> 6;
    int bin = blockIdx.x;
    unsigned sbeg = (unsigned)bin * CAPF;
    int n  = min((int)(cursor[bin] - sbeg), CAPF);
    int nr = (n + 1023) >> 10;                 // rounds (<=11)

    unsigned* hw = (unsigned*)h16;
    for (int i = tid; i < 16 * RPB / 2; i += 1024) hw[i] = 0u;
    __syncthreads();

    // phase A: ballot histogram by lrow (10 bits) — cached loads
    for (int c = 0; c < nr; ++c) {
        int idx = c * 1024 + tid;
        bool v = idx < n;
        unsigned key = 0u;
        if (v) key = recB[sbeg + idx] & (RPB - 1u);
        int rank, gsz;
        brank<10>(key, v, lane, rank, gsz);
        if (v && rank == 0)
            h16[wv][key] = (unsigned short)(h16[wv][key] + (unsigned)gsz);
    }
    __syncthreads();

    // scan 1024 row-bins (1/thread): wave prefix into h16, block scan -> ptr_
    {
        unsigned t0 = 0;
#pragma unroll
        for (int ww = 0; ww < 16; ++ww) {
            unsigned a = h16[ww][tid]; h16[ww][tid] = (unsigned short)t0; t0 += a;
        }
        unsigned incl = t0;
        for (int off = 1; off < 64; off <<= 1) {
            unsigned m = __shfl_up(incl, off, 64);
            if ((tid & 63) >= off) incl += m;
        }
        if ((tid & 63) == 63) wsum[tid >> 6] = incl;
        __syncthreads();
        unsigned pre = 0;
        for (int k = 0; k < (tid >> 6); ++k) pre += wsum[k];
        unsigned ex = pre + incl - t0;
        ptr_[tid] = (unsigned short)ex;
        if (tid == 1023) ptr_[RPB] = (unsigned short)n;
#pragma unroll
        for (int ww = 0; ww < 16; ++ww)
            h16[ww][tid] = (unsigned short)(h16[ww][tid] + ex);
    }
    __syncthreads();

    // phase B: reload (L2-hot), place payload into LDS sorted order
    for (int c = 0; c < nr; ++c) {
        int idx = c * 1024 + tid;
        bool v = idx < n;
        unsigned key = 0u, pay = 0u;
        if (v) {
            key = recB[sbeg + idx] & (RPB - 1u);
            pay = recA[sbeg + idx];
        }
        int rank, gsz;
        brank<10>(key, v, lane, rank, gsz);
        unsigned cur = h16[wv][key];
        if (v && rank == 0)
            h16[wv][key] = (unsigned short)(cur + (unsigned)gsz);
        if (v) srt[cur + (unsigned)rank] = pay;
    }
    __syncthreads();

    // gather: 1 thread per row, register accumulate, 2-deep pipeline
    int r = tid;
    float a[16];
#pragma unroll
    for (int k = 0; k < 16; ++k) a[k] = 0.f;
    {
        int p0 = (int)ptr_[r];
        int p1 = (int)ptr_[r + 1];
        uint4 lo = make_uint4(0, 0, 0, 0), hi = lo;
        unsigned u = 0u;
        int p = p0;
        if (p < p1) {
            u = srt[p];
            const uint4* q = reinterpret_cast<const uint4*>(xT + (size_t)(u & 0xFFFFFu) * 8);
            lo = q[0]; hi = q[1];
        }
        while (p < p1) {
            int pn = p + 1;
            unsigned un = 0u;
            uint4 lon = make_uint4(0, 0, 0, 0), hin = lon;
            if (pn < p1) {
                un = srt[pn];
                const uint4* qn = reinterpret_cast<const uint4*>(xT + (size_t)(un & 0xFFFFFu) * 8);
                lon = qn[0]; hin = qn[1];
            }
            float wt = wt_tab[u >> 20];
            fma8(a, wt, lo, 0);
            fma8(a, wt, hi, 8);
            u = un; lo = lon; hi = hin; p = pn;
        }
    }
    int gr = bin * RPB + r;
    if (gr < NROW) {
#pragma unroll
        for (int k = 0; k < 16; ++k)
            __builtin_nontemporal_store(a[k], out + (size_t)k * NROW + gr);
    }
}

// ---------------- fallback path (atomic scatter, needs only 51.2MB) ----

__global__ __launch_bounds__(256) void k_scatter(const int* __restrict__ rows,
                                                 const int* __restrict__ cols,
                                                 const int* __restrict__ et,
                                                 const float* __restrict__ w,
                                                 const unsigned* __restrict__ xT,
                                                 unsigned short* __restrict__ outT,
                                                 int E) {
    long long tid = (long long)blockIdx.x * 256 + threadIdx.x;
    long long e = tid >> 3;
    if (e >= E) return;
    int j = (int)(tid & 7);
    int r = __builtin_nontemporal_load(rows + e);
    int c = __builtin_nontemporal_load(cols + e);
    int t = __builtin_nontemporal_load(et + e);
    float wt = w[t];
    unsigned px = xT[(size_t)c * 8 + j];
    float x0 = bf2f((unsigned short)(px & 0xffffu));
    float x1 = bf2f((unsigned short)(px >> 16));
    unsigned short b0 = f2bf(wt * x0);
    unsigned short b1 = f2bf(wt * x1);
    unsigned data = (unsigned)b0 | ((unsigned)b1 << 16);
    unsigned short* dst = outT + ((size_t)r * 16 + 2 * j);
    asm volatile("global_atomic_pk_add_bf16 %0, %1, off"
                 :: "v"(dst), "v"(data) : "memory");
}

__global__ __launch_bounds__(256) void k_transpose_out(const unsigned* __restrict__ outT,
                                                       float* __restrict__ out) {
    int r = blockIdx.x * 256 + threadIdx.x;
    if (r >= NROW) return;
    const uint4* src = reinterpret_cast<const uint4*>(outT + (size_t)r * 8);
    uint4 v0 = src[0], v1 = src[1];
    unsigned p[8] = {v0.x, v0.y, v0.z, v0.w, v1.x, v1.y, v1.z, v1.w};
#pragma unroll
    for (int b = 0; b < 8; ++b) {
        out[(size_t)(2 * b)     * NROW + r] = bf2f((unsigned short)(p[b] & 0xffffu));
        out[(size_t)(2 * b + 1) * NROW + r] = bf2f((unsigned short)(p[b] >> 16));
    }
}

extern "C" void kernel_launch(void* const* d_in, const int* in_sizes, int n_in,
                              void* d_out, int out_size, void* d_ws, size_t ws_size,
                              hipStream_t stream) {
    const float* x    = (const float*)d_in[0];
    const float* w    = (const float*)d_in[1];
    const int*   rows = (const int*)d_in[2];
    const int*   cols = (const int*)d_in[3];
    const int*   et   = (const int*)d_in[4];
    const int    E    = in_sizes[2];

    float* out = (float*)d_out;

    // ws layout: xT 25.6MB | recA u32[NBIN*CAPF] | recB u16[NBIN*CAPF] | cursor[1024]
    size_t xT_b    = (size_t)NCOL * 8 * 4;            // 25,600,000
    size_t slabN   = (size_t)NBIN * CAPF;             // 8,808,448 recs
    size_t rA_off  = xT_b;
    size_t rB_off  = rA_off + slabN * 4;
    size_t aux_off = (rB_off + slabN * 2 + 255) & ~(size_t)255;
    size_t needed  = aux_off + 1024 * 4;              // ~78.7MB

    unsigned* xT = (unsigned*)d_ws;

    if (ws_size >= needed) {
        unsigned*       recA   = (unsigned*)((char*)d_ws + rA_off);
        unsigned short* recB   = (unsigned short*)((char*)d_ws + rB_off);
        unsigned*       cursor = (unsigned*)((char*)d_ws + aux_off);

        k_init<<<1, 1024, 0, stream>>>(cursor);
        k_transpose_x<<<NCOL / 256, 256, 0, stream>>>(x, xT);

        int pblocks = (E + PR - 1) / PR;
        k_place<<<pblocks, PT, 0, stream>>>(rows, cols, et, cursor, recA, recB, E);
        k_pull<<<NBIN, 1024, 0, stream>>>(cursor, recA, recB, w, xT, out);
    } else {
        // fallback: pk_add_bf16 atomic scatter (51.2MB ws)
        unsigned short* outT = (unsigned short*)d_ws;
        unsigned*       xT2  = (unsigned*)((char*)d_ws + (size_t)NROW * BNUM * 2);

        hipMemsetAsync(outT, 0, (size_t)NROW * BNUM * 2, stream);
        k_transpose_x<<<NCOL / 256, 256, 0, stream>>>(x, xT2);

        long long total = (long long)E * 8;
        int blocks = (int)((total + 255) / 256);
        k_scatter<<<blocks, 256, 0, stream>>>(rows, cols, et, w, xT2, outT, E);
        k_transpose_out<<<NROW / 256, 256, 0, stream>>>((const unsigned*)outT, out);
    }
}